// Round 8
// baseline (291.294 us; speedup 1.0000x reference)
//
#include <hip/hip_runtime.h>

// ---------------- problem constants ----------------
#define NN   10000     // nodes
#define E0   160000    // raw edges
#define ET   170000    // edges + self loops
#define DIN  165       // input channels
#define KP   192       // DIN padded to 32x for MFMA K-loop
#define HID  1024      // 8 heads * 128
#define NH   8
#define AP   200       // gemm1 A-tile LDS pitch (shorts): 2-way banks only, 16B rows
#define CP   136       // gemm1 C-stage LDS pitch (shorts)
#define K2P  1032      // LDS row pitch for gemm2 B
#define BNROW 64       // fuseA bn1 tile rows
#define BNBLK 157      // ceil(NN/BNROW)

// dtypes (settled r6): ALL float tensors f32, edge_index int32, OUTPUT f32.

typedef __bf16 bf16x8 __attribute__((ext_vector_type(8)));
typedef float  f32x4  __attribute__((ext_vector_type(4)));
typedef float  f32x2  __attribute__((ext_vector_type(2)));

__device__ __forceinline__ float bf2f(unsigned short u) {
    unsigned int i = ((unsigned int)u) << 16;
    return __builtin_bit_cast(float, i);
}
__device__ __forceinline__ unsigned short f2bf(float f) {
    unsigned int i = __builtin_bit_cast(unsigned int, f);
    i += 0x7fffu + ((i >> 16) & 1u);   // round-to-nearest-even
    return (unsigned short)(i >> 16);
}
__device__ __forceinline__ float fin(float x) {
    return fminf(fmaxf(x, -1e30f), 1e30f);
}
__device__ __forceinline__ int clampi(int s) {
    return min(max(s, 0), NN - 1);
}
__device__ __forceinline__ void unpack8(uint4 u, float* f) {
    f[0]=bf2f((unsigned short)(u.x)); f[1]=bf2f((unsigned short)(u.x>>16));
    f[2]=bf2f((unsigned short)(u.y)); f[3]=bf2f((unsigned short)(u.y>>16));
    f[4]=bf2f((unsigned short)(u.z)); f[5]=bf2f((unsigned short)(u.z>>16));
    f[6]=bf2f((unsigned short)(u.w)); f[7]=bf2f((unsigned short)(u.w>>16));
}
// one packed u32 (2 bf16) -> f32x2 in 2 VALU ops (lshl / and)
__device__ __forceinline__ f32x2 up2(unsigned int u) {
    f32x2 r;
    r.x = __builtin_bit_cast(float, u << 16);
    r.y = __builtin_bit_cast(float, u & 0xffff0000u);
    return r;
}

// ---------------- debug ----------------
__global__ __launch_bounds__(256) void debug_fill(float* __restrict__ out, float val) {
    int i = blockIdx.x * 256 + threadIdx.x;
    if (i < NN) out[i] = val;
}

// ---------------- FUSED A: bn1_stats LDS-stream (157 blocks) + edge_hist --------
__global__ __launch_bounds__(256) void fuseA_kernel(const float* __restrict__ x,
                                                    float* __restrict__ colsum, float* __restrict__ colsq,
                                                    const int* __restrict__ ei, int* __restrict__ deg) {
    __shared__ float xs[BNROW * DIN];   // 42.24 KB flat tile
    const int b = blockIdx.x;
    const int tid = threadIdx.x;
    if (b < BNBLK) {
        const int r0 = b * BNROW;
        const int nrows = min(BNROW, NN - r0);
        const int total = nrows * DIN;          // even (nrows even)
        const float2* src = (const float2*)(x + (size_t)r0 * DIN);
        float2* dstl = (float2*)xs;
        for (int idx = tid; idx < (total >> 1); idx += 256)
            dstl[idx] = src[idx];
        __syncthreads();
        const int c = tid;
        if (c >= DIN) return;
        float a0=0,a1=0,a2=0,a3=0, q0=0,q1=0,q2=0,q3=0;
        int r = 0;
        for (; r + 3 < nrows; r += 4) {
            float v0 = xs[(r    ) * DIN + c];
            float v1 = xs[(r + 1) * DIN + c];
            float v2 = xs[(r + 2) * DIN + c];
            float v3 = xs[(r + 3) * DIN + c];
            a0 += v0; q0 += v0 * v0;
            a1 += v1; q1 += v1 * v1;
            a2 += v2; q2 += v2 * v2;
            a3 += v3; q3 += v3 * v3;
        }
        for (; r < nrows; ++r) {
            float v = xs[r * DIN + c];
            a0 += v; q0 += v * v;
        }
        atomicAdd(&colsum[c], (a0 + a1) + (a2 + a3));
        atomicAdd(&colsq[c],  (q0 + q1) + (q2 + q3));
    } else {
        int e = (b - BNBLK) * 256 + tid;
        if (e >= ET) return;
        int d = (e < E0) ? ei[E0 + e] : (e - E0);
        atomicAdd(&deg[clampi(d)], 1);
    }
}

// ---------------- FUSED B: scan (block 0, 1024 thr) + bn1_apply (blocks>=1) -----
__global__ __launch_bounds__(1024) void fuseB_kernel(
    const int* __restrict__ deg,
    int* __restrict__ offs, int* __restrict__ cur, int* __restrict__ perm,
    const float* __restrict__ x,
    const float* __restrict__ colsum, const float* __restrict__ colsq,
    const float* __restrict__ gamma, const float* __restrict__ beta,
    unsigned short* __restrict__ hn) {
    if (blockIdx.x != 0) {
        int idx = (blockIdx.x - 1) * 1024 + threadIdx.x;
        if (idx >= NN * KP) return;
        int r = idx / KP, c = idx - r * KP;
        float v = 0.f;
        if (c < DIN) {
            float mu  = colsum[c] * (1.f / NN);
            float var = fmaxf(colsq[c] * (1.f / NN) - mu * mu, 0.f);
            float a = gamma[c] * rsqrtf(var + 1e-5f);
            float b = beta[c] - mu * a;
            v = fin(x[(size_t)r * DIN + c] * a + b);
        }
        hn[idx] = f2bf(v);
        return;
    }
    __shared__ int wsum[16];
    __shared__ int bins[64];
    __shared__ int bcur[64];
    const int tid = threadIdx.x;
    const int base = tid * 10;
    int loc[10];
    int run = 0;
    #pragma unroll
    for (int j = 0; j < 10; ++j) {
        int idx = base + j;
        int v = (idx < NN) ? deg[idx] : 0;
        loc[j] = run;
        run += v;
    }
    const int lane = tid & 63;
    const int w = tid >> 6;
    int inc = run;
    #pragma unroll
    for (int s = 1; s < 64; s <<= 1) {
        int t = __shfl_up(inc, s);
        if (lane >= s) inc += t;
    }
    if (lane == 63) wsum[w] = inc;
    if (tid < 64) bins[tid] = 0;
    __syncthreads();
    int woff = 0;
    #pragma unroll
    for (int k = 0; k < 16; ++k) woff += (k < w) ? wsum[k] : 0;
    const int toff = woff + inc - run;
    #pragma unroll
    for (int j = 0; j < 10; ++j) {
        int idx = base + j;
        if (idx < NN) {
            int e = toff + loc[j]; offs[idx] = e; cur[idx] = e;
            atomicAdd(&bins[63 - min(deg[idx], 63)], 1);   // descending-degree bucket
        }
    }
    if (tid == 1023) offs[NN] = woff + inc;
    __syncthreads();
    if (tid < 64) {   // wave 0: exclusive scan of 64 bins
        int v = bins[tid];
        int binc = v;
        #pragma unroll
        for (int s = 1; s < 64; s <<= 1) {
            int t = __shfl_up(binc, s);
            if (tid >= s) binc += t;
        }
        bcur[tid] = binc - v;
    }
    __syncthreads();
    #pragma unroll
    for (int j = 0; j < 10; ++j) {
        int idx = base + j;
        if (idx < NN) {
            int pos = atomicAdd(&bcur[63 - min(deg[idx], 63)], 1);
            perm[pos] = idx;
        }
    }
}

// ---------------- FUSED C: w1_transpose (192 blocks) + edge_scatter (665) -------
__global__ __launch_bounds__(256) void fuseC_kernel(const float* __restrict__ wl,
                                                    const float* __restrict__ wr,
                                                    unsigned short* __restrict__ wlt,
                                                    unsigned short* __restrict__ wrt,
                                                    const int* __restrict__ ei,
                                                    int* __restrict__ cur, int* __restrict__ ssrc) {
    const int b = blockIdx.x;
    if (b < 192) {
        const int z  = b / 96;
        const int rm = b - z * 96;
        const int ky = rm / 6;
        const int kx = rm - ky * 6;
        const float* src    = z ? wr  : wl;
        unsigned short* dst = z ? wrt : wlt;
        __shared__ float ts[32][65];
        const int k0 = kx * 32;
        const int n0 = ky * 64;
        const int tid = threadIdx.x;
        for (int idx = tid; idx < 32 * 64; idx += 256) {
            int k = idx >> 6, n = idx & 63;
            ts[k][n] = (k0 + k < DIN) ? src[(size_t)(k0 + k) * HID + n0 + n] : 0.f;
        }
        __syncthreads();
        for (int idx = tid; idx < 64 * 32; idx += 256) {
            int n = idx >> 5, k = idx & 31;
            dst[(size_t)(n0 + n) * KP + k0 + k] = f2bf(ts[k][n]);
        }
    } else {
        int e = (b - 192) * 256 + threadIdx.x;
        if (e >= ET) return;
        int s, d;
        if (e < E0) { s = ei[e]; d = ei[E0 + e]; }
        else        { s = e - E0; d = e - E0; }
        int pos = atomicAdd(&cur[clampi(d)], 1);
        if (pos >= 0 && pos < ET) ssrc[pos] = clampi(s);
    }
}

// ---------------- GEMM1 r20: 64x128 tiles, B-in-regs, batched A staging ---------
__global__ __launch_bounds__(256) void gemm1_kernel(
    const unsigned short* __restrict__ hn,
    const unsigned short* __restrict__ wlt,  // [HID][KP] bf16
    const unsigned short* __restrict__ wrt,
    const float* __restrict__ bl,
    const float* __restrict__ br,
    unsigned short* __restrict__ xl,
    unsigned short* __restrict__ xr) {
    __shared__ unsigned short as[64 * AP];   // 25.6 KB: A-tile, then C staging
    const int tid  = threadIdx.x;
    const int lane = tid & 63;
    const int wave = tid >> 6;
    const int col  = lane & 15;
    const int q    = lane >> 4;

    const int m0 = blockIdx.x * 64;
    const int z  = blockIdx.y >> 3;            // 0 = L half, 1 = R half
    const int nb = (blockIdx.y & 7) * 128;     // col base within that half
    const unsigned short* wt = z ? wrt : wlt;

    // ---- B fragments: 12 batched uint4 loads (L2-resident W'), held in regs ----
    bf16x8 B[2][6];
    {
        const int bc0 = nb + wave * 32 + col;
        #pragma unroll
        for (int nt = 0; nt < 2; ++nt) {
            const unsigned short* wp = wt + (size_t)(bc0 + nt * 16) * KP + q * 8;
            #pragma unroll
            for (int kt = 0; kt < 6; ++kt)
                B[nt][kt] = __builtin_bit_cast(bf16x8, *(const uint4*)(wp + kt * 32));
        }
    }

    // ---- A-tile staging: 6 batched global loads -> 6 LDS writes ----
    {
        const int r  = tid >> 2;               // 0..63
        const int s0 = (tid & 3) * 48;         // short offset within row
        const int grow = m0 + r;
        uint4 t0 = {0,0,0,0}, t1 = t0, t2 = t0, t3 = t0, t4 = t0, t5 = t0;
        if (grow < NN) {
            const unsigned short* gp = hn + (size_t)grow * KP + s0;
            t0 = *(const uint4*)(gp);
            t1 = *(const uint4*)(gp + 8);
            t2 = *(const uint4*)(gp + 16);
            t3 = *(const uint4*)(gp + 24);
            t4 = *(const uint4*)(gp + 32);
            t5 = *(const uint4*)(gp + 40);
        }
        unsigned short* lp = as + r * AP + s0;
        *(uint4*)(lp)      = t0;
        *(uint4*)(lp + 8)  = t1;
        *(uint4*)(lp + 16) = t2;
        *(uint4*)(lp + 24) = t3;
        *(uint4*)(lp + 32) = t4;
        *(uint4*)(lp + 40) = t5;
    }
    __syncthreads();

    // ---- MFMA: 4 m-tiles x 2 n-tiles x 6 k = 48 per wave ----
    f32x4 acc[4][2];
    #pragma unroll
    for (int mi = 0; mi < 4; ++mi)
        for (int nt = 0; nt < 2; ++nt)
            acc[mi][nt][0] = acc[mi][nt][1] = acc[mi][nt][2] = acc[mi][nt][3] = 0.f;

    #pragma unroll
    for (int kt = 0; kt < 6; ++kt) {
        const int kk = kt * 32 + q * 8;
        bf16x8 A[4];
        #pragma unroll
        for (int mi = 0; mi < 4; ++mi)
            A[mi] = __builtin_bit_cast(bf16x8, *(const uint4*)(as + (mi * 16 + col) * AP + kk));
        #pragma unroll
        for (int mi = 0; mi < 4; ++mi) {
            acc[mi][0] = __builtin_amdgcn_mfma_f32_16x16x32_bf16(A[mi], B[0][kt], acc[mi][0], 0, 0, 0);
            acc[mi][1] = __builtin_amdgcn_mfma_f32_16x16x32_bf16(A[mi], B[1][kt], acc[mi][1], 0, 0, 0);
        }
    }

    // ---- epilogue: bias + fin -> LDS C [64][CP], then full 256B-row stores ----
    __syncthreads();                            // A reads done; reuse as[] for C
    #pragma unroll
    for (int nt = 0; nt < 2; ++nt) {
        const int lc = wave * 32 + nt * 16 + col;   // 0..127
        const float bv = (z ? br : bl)[nb + lc];
        #pragma unroll
        for (int mi = 0; mi < 4; ++mi) {
            #pragma unroll
            for (int r = 0; r < 4; ++r) {
                const int lr = mi * 16 + q * 4 + r;
                as[lr * CP + lc] = f2bf(fin(acc[mi][nt][r] + bv));
            }
        }
    }
    __syncthreads();
    {
        const int r  = tid >> 2;               // 0..63
        const int sg = (tid & 3) * 32;         // 32-col (64B) segment
        const int grow = m0 + r;
        if (grow < NN) {
            unsigned short* dst = (z ? xr : xl) + (size_t)grow * HID + nb + sg;
            const unsigned short* sp = as + r * CP + sg;
            *(uint4*)(dst)      = *(const uint4*)(sp);
            *(uint4*)(dst + 8)  = *(const uint4*)(sp + 8);
            *(uint4*)(dst + 16) = *(const uint4*)(sp + 16);
            *(uint4*)(dst + 24) = *(const uint4*)(sp + 24);
        }
    }
}

// ---------------- GAT1 r23: quarter-split (4 XCD-pinned channel quarters) -------
// r22 falsified the TLP theory: 3 structures converge at ~3.4 TB/s -> bytes/XCD
// is the binding constraint. r17 proved XCD pinning + channel split cuts FETCH
// 6x but its skeleton cost x8 lost. r23 interpolates: wave = (node, quarter);
// quarter = blockIdx&3 -> XCD-pinned (round-robin); working set 5.1MB ~ L2.
// Skeleton controlled by LANE-HALF EDGE PAIRING: lanes 0-31 even edges, 32-63
// odd edges (8 ch/lane uint4, 16-lane head groups) -> one wave-iter = 2 edges,
// per-edge instructions ~= r15. Cross-half combine: 9 shuffles once. No LDS.
// Alias (agg=xr1) safe: wave reads its own (i, quarter) slice before writing it.
__global__ __launch_bounds__(256) void gat1_node(
    const unsigned short* __restrict__ xl1, const unsigned short* xr1,
    const float* __restrict__ att1, const float* __restrict__ bias1,
    const int* __restrict__ offs, const int* __restrict__ ssrc,
    const int* __restrict__ perm,
    unsigned short* agg) {
    const int lane    = threadIdx.x & 63;
    const int wv      = threadIdx.x >> 6;
    const int quarter = blockIdx.x & 3;        // -> XCD pinning (round-robin)
    const int ngrp    = blockIdx.x >> 2;
    const int i  = perm[ngrp * 4 + wv];        // degree-descending
    const int e0 = offs[i];
    const int e1 = max(offs[i + 1], e0 + 1);   // >=1 edge (self-loop)
    const int cl    = lane & 31;               // channel slot (8 ch)
    const int halfB = lane >> 5;               // 0: even edges, 1: odd edges
    const int choff = quarter * 256 + cl * 8;  // 8 channels of one head

    f32x2 xr2[4], at2[4], o2[4];
    {
        uint4 u = *(const uint4*)(xr1 + (size_t)i * HID + choff);
        xr2[0] = up2(u.x); xr2[1] = up2(u.y); xr2[2] = up2(u.z); xr2[3] = up2(u.w);
        float4 a0 = *(const float4*)(att1 + choff);
        float4 a1 = *(const float4*)(att1 + choff + 4);
        at2[0].x = a0.x; at2[0].y = a0.y; at2[1].x = a0.z; at2[1].y = a0.w;
        at2[2].x = a1.x; at2[2].y = a1.y; at2[3].x = a1.z; at2[3].y = a1.w;
        #pragma unroll
        for (int j = 0; j < 4; ++j) { o2[j].x = 0.f; o2[j].y = 0.f; }
    }
    float s = 0.f;

    const int trips = (e1 - e0 + 1) >> 1;
    for (int t = 0; t < trips; ++t) {
        const int e  = e0 + 2 * t + halfB;
        const bool ok = (e < e1);
        const int sidx = clampi(ssrc[min(e, e1 - 1)]);
        const uint4 u = *(const uint4*)(xl1 + (size_t)sidx * HID + choff);
        f32x2 x0 = up2(u.x), x1 = up2(u.y), x2 = up2(u.z), x3 = up2(u.w);
        f32x2 v0 = x0 + xr2[0], v1 = x1 + xr2[1], v2 = x2 + xr2[2], v3 = x3 + xr2[3];
        v0 = __builtin_elementwise_max(v0, 0.2f * v0);
        v1 = __builtin_elementwise_max(v1, 0.2f * v1);
        v2 = __builtin_elementwise_max(v2, 0.2f * v2);
        v3 = __builtin_elementwise_max(v3, 0.2f * v3);
        f32x2 p = at2[0] * v0;
        p = __builtin_elementwise_fma(at2[1], v1, p);
        p = __builtin_elementwise_fma(at2[2], v2, p);
        p = __builtin_elementwise_fma(at2[3], v3, p);
        float r = p.x + p.y;
        r += __shfl_xor(r, 1); r += __shfl_xor(r, 2);
        r += __shfl_xor(r, 4); r += __shfl_xor(r, 8);   // 16-lane head-group dot
        const float a = ok ? __expf(fminf(fin(r), 50.f)) : 0.f;
        s += a;
        f32x2 av; av.x = a; av.y = a;
        o2[0] = __builtin_elementwise_fma(av, x0, o2[0]);
        o2[1] = __builtin_elementwise_fma(av, x1, o2[1]);
        o2[2] = __builtin_elementwise_fma(av, x2, o2[2]);
        o2[3] = __builtin_elementwise_fma(av, x3, o2[3]);
    }

    // combine even/odd halves (lane l <-> l+32, same channels)
    s += __shfl_xor(s, 32);
    #pragma unroll
    for (int j = 0; j < 4; ++j) {
        o2[j].x += __shfl_xor(o2[j].x, 32);
        o2[j].y += __shfl_xor(o2[j].y, 32);
    }

    if (halfB == 0) {
        const float inv = 1.f / (s + 1e-16f);
        float4 b0 = *(const float4*)(bias1 + choff);
        float4 b1 = *(const float4*)(bias1 + choff + 4);
        float bb[8] = {b0.x, b0.y, b0.z, b0.w, b1.x, b1.y, b1.z, b1.w};
        unsigned short ov[8];
        #pragma unroll
        for (int j = 0; j < 4; ++j) {
            ov[2*j]   = f2bf(fin(o2[j].x * inv + bb[2*j]));
            ov[2*j+1] = f2bf(fin(o2[j].y * inv + bb[2*j+1]));
        }
        *(uint4*)(agg + (size_t)i * HID + choff) = *(const uint4*)ov;
    }
}

// ---------------- BN2 stats over agg [NN,HID] bf16 ----------------
__global__ __launch_bounds__(256) void bn2_stats(const unsigned short* __restrict__ agg,
                                                 float* __restrict__ colsum, float* __restrict__ colsq) {
    __shared__ float mrg[128 * 16];   // 8 KB: half-1 partials
    const int tid  = threadIdx.x;
    const int half = tid >> 7;        // 0/1
    const int cc   = (tid & 127) * 8; // column base (8 cols per thread)
    const int r0   = blockIdx.x * 80 + half;
    float s[8], q[8];
    #pragma unroll
    for (int j = 0; j < 8; ++j) { s[j] = 0.f; q[j] = 0.f; }
    #pragma unroll 4
    for (int rr = 0; rr < 40; ++rr) {
        const int r = r0 + rr * 2;
        uint4 u = *(const uint4*)(agg + (size_t)r * HID + cc);
        float v[8];
        unpack8(u, v);
        #pragma unroll
        for (int j = 0; j < 8; ++j) { s[j] += v[j]; q[j] += v[j] * v[j]; }
    }
    if (half) {
        float* m = &mrg[(tid & 127) * 16];
        #pragma unroll
        for (int j = 0; j < 8; ++j) { m[j] = s[j]; m[8 + j] = q[j]; }
    }
    __syncthreads();
    if (!half) {
        const float* m = &mrg[tid * 16];
        #pragma unroll
        for (int j = 0; j < 8; ++j) {
            atomicAdd(&colsum[cc + j], s[j] + m[j]);
            atomicAdd(&colsq[cc + j],  q[j] + m[8 + j]);
        }
    }
}

// ---------------- GEMM2 (K split across 4 waves + LDS reduce; grid 625) ----
__global__ __launch_bounds__(256) void gemm2_kernel(
    const unsigned short* __restrict__ agg,
    const float* __restrict__ colsum, const float* __restrict__ colsq,
    const float* __restrict__ gamma, const float* __restrict__ beta,
    const float* __restrict__ wl2, const float* __restrict__ wr2,
    const float* __restrict__ bl2, const float* __restrict__ br2,
    float* __restrict__ xl2, float* __restrict__ xr2) {
    __shared__ unsigned short bs[16 * K2P];   // 33 KB
    __shared__ float a2s[HID], b2s[HID];      // 8 KB affine table
    __shared__ float red[4 * 64 * 4];         // 4 KB wave partials
    const int tid  = threadIdx.x;
    const int lane = tid & 63;
    const int wave = tid >> 6;
    const int col  = lane & 15;
    const int q    = lane >> 4;

    for (int idx = tid; idx < 16 * HID; idx += 256) {
        int n = idx >> 10, k = idx & (HID - 1);
        float v = (n < 8) ? wl2[k * 8 + n] : wr2[k * 8 + (n - 8)];
        bs[n * K2P + k] = f2bf(v);
    }
    for (int cc = tid; cc < HID; cc += 256) {
        float mu  = colsum[cc] * (1.f / NN);
        float var = fmaxf(colsq[cc] * (1.f / NN) - mu * mu, 0.f);
        float a = gamma[cc] * rsqrtf(var + 1e-5f);
        a2s[cc] = a; b2s[cc] = beta[cc] - mu * a;
    }
    __syncthreads();

    const int m0 = blockIdx.x * 16;
    const int am = m0 + col;

    // hoist all 8 independent A-row loads
    uint4 u[8];
    #pragma unroll
    for (int t = 0; t < 8; ++t) {
        const int kk = (wave * 8 + t) * 32 + q * 8;
        u[t] = *(const uint4*)(agg + (size_t)am * HID + kk);
    }

    f32x4 acc;
    acc[0] = acc[1] = acc[2] = acc[3] = 0.f;
    #pragma unroll
    for (int t = 0; t < 8; ++t) {
        const int kk = (wave * 8 + t) * 32 + q * 8;
        float xv[8];
        unpack8(u[t], xv);
        unsigned short hv[8];
        #pragma unroll
        for (int j = 0; j < 8; ++j) {
            float v = xv[j] * a2s[kk + j] + b2s[kk + j];
            v = fmaxf(v, 0.01f * v);          // leaky 0.01
            hv[j] = f2bf(fin(v));
        }
        bf16x8 af = __builtin_bit_cast(bf16x8, *(const uint4*)hv);
        bf16x8 bf = __builtin_bit_cast(bf16x8, *(const uint4*)&bs[col * K2P + kk]);
        acc = __builtin_amdgcn_mfma_f32_16x16x32_bf16(af, bf, acc, 0, 0, 0);
    }

    *(f32x4*)&red[(wave * 64 + lane) * 4] = acc;
    __syncthreads();
    if (wave == 0) {
        f32x4 a0 = *(const f32x4*)&red[lane * 4];
        f32x4 a1 = *(const f32x4*)&red[(64 + lane) * 4];
        f32x4 a2 = *(const f32x4*)&red[(128 + lane) * 4];
        f32x4 a3 = *(const f32x4*)&red[(192 + lane) * 4];
        acc = (a0 + a1) + (a2 + a3);
        const float bv = (col < 8) ? bl2[col] : br2[col - 8];
        float* outp = (col < 8) ? (xl2 + col) : (xr2 + (col - 8));
        #pragma unroll
        for (int r = 0; r < 4; ++r) {
            const int row = m0 + q * 4 + r;
            outp[row * 8] = fin(acc[r] + bv);
        }
    }
}

// ---------------- GAT2 single-pass (degree-sorted order) ----------------
__global__ __launch_bounds__(256) void gat2_node(
    const float* __restrict__ xl2, const float* __restrict__ xr2,
    const float* __restrict__ att2, const float* __restrict__ bias2,
    const int* __restrict__ offs, const int* __restrict__ ssrc,
    const int* __restrict__ perm,
    float* __restrict__ out) {
    const int lane = threadIdx.x & 63;
    const int wave = threadIdx.x >> 6;
    const int i = perm[blockIdx.x * 4 + wave];
    const int h = lane & 7, slot = lane >> 3;
    const int e0 = offs[i];
    const int e1 = max(offs[i + 1], e0);
    const float xr_h = xr2[i * 8 + h];
    const float att_h = att2[h];
    float ssum = 0.f, wsum = 0.f;
    for (int eb = e0; eb < e1; eb += 8) {
        int e = eb + slot;
        if (e < e1) {
            float xlv = xl2[clampi(ssrc[e]) * 8 + h];
            float v = xlv + xr_h;
            v = fmaxf(v, 0.2f * v);
            float a = __expf(fminf(fin(att_h * v), 50.f));
            ssum += a; wsum += a * xlv;
        }
    }
    ssum += __shfl_xor(ssum, 8); ssum += __shfl_xor(ssum, 16); ssum += __shfl_xor(ssum, 32);
    wsum += __shfl_xor(wsum, 8); wsum += __shfl_xor(wsum, 16); wsum += __shfl_xor(wsum, 32);
    float v = fin(wsum / (ssum + 1e-16f));
    v += __shfl_xor(v, 1); v += __shfl_xor(v, 2); v += __shfl_xor(v, 4);
    if (lane == 0) out[i] = fin(v * 0.125f + bias2[0]);
}

// ---------------- launch ----------------
extern "C" void kernel_launch(void* const* d_in, const int* in_sizes, int n_in,
                              void* d_out, int out_size, void* d_ws, size_t ws_size,
                              hipStream_t stream) {
    float* out = (float*)d_out;   // reference output dtype is float32

    static const int expected[18] = {
        NN * DIN, DIN, DIN, DIN * HID, HID, DIN * HID, HID, HID, HID,
        HID, HID, HID * NH, NH, HID * NH, NH, NH, 1, 2 * E0
    };
    if (n_in != 18) {
        debug_fill<<<(NN + 255) / 256, 256, 0, stream>>>(out, 8192.f + 64.f * (float)n_in);
        return;
    }
    for (int i = 0; i < 18; ++i) {
        if (in_sizes[i] != expected[i]) {
            debug_fill<<<(NN + 255) / 256, 256, 0, stream>>>(out, 4096.f + 32.f * (float)i);
            return;
        }
    }

    const float* x      = (const float*)d_in[0];
    const float* gamma1 = (const float*)d_in[1];
    const float* beta1  = (const float*)d_in[2];
    const float* Wl1    = (const float*)d_in[3];
    const float* bl1    = (const float*)d_in[4];
    const float* Wr1    = (const float*)d_in[5];
    const float* br1    = (const float*)d_in[6];
    const float* att1   = (const float*)d_in[7];
    const float* bias1  = (const float*)d_in[8];
    const float* gamma2 = (const float*)d_in[9];
    const float* beta2  = (const float*)d_in[10];
    const float* Wl2    = (const float*)d_in[11];
    const float* bl2    = (const float*)d_in[12];
    const float* Wr2    = (const float*)d_in[13];
    const float* br2    = (const float*)d_in[14];
    const float* att2   = (const float*)d_in[15];
    const float* bias2  = (const float*)d_in[16];
    const int*   ei     = (const int*)d_in[17];

    char* p = (char*)d_ws;
    auto alloc = [&](size_t bytes) -> void* {
        void* r = (void*)p;
        p += (bytes + 255) & ~(size_t)255;
        return r;
    };
    unsigned short* xl1  = (unsigned short*)alloc((size_t)NN * HID * 2);  // 20.48 MB
    unsigned short* xr1  = (unsigned short*)alloc((size_t)NN * HID * 2);  // 20.48 MB
    unsigned short* agg  = xr1;                                           // ALIAS (see gat1_node)
    unsigned short* hn   = (unsigned short*)alloc((size_t)NN * KP * 2);   // 3.84 MB
    unsigned short* wlt  = (unsigned short*)alloc((size_t)HID * KP * 2);  // 0.39 MB
    unsigned short* wrt  = (unsigned short*)alloc((size_t)HID * KP * 2);  // 0.39 MB
    float*          xl2  = (float*)alloc((size_t)NN * 8 * 4);
    float*          xr2  = (float*)alloc((size_t)NN * 8 * 4);
    int*            offs = (int*)alloc((NN + 1) * 4);
    int*            cur  = (int*)alloc(NN * 4);
    int*            ssrc = (int*)alloc(ET * 4);
    int*            perm = (int*)alloc(NN * 4);
    char* zbase = p;
    float* colsum1 = (float*)alloc(DIN * 4);
    float* colsq1  = (float*)alloc(DIN * 4);
    float* colsum2 = (float*)alloc(HID * 4);
    float* colsq2  = (float*)alloc(HID * 4);
    int*   deg     = (int*)alloc(NN * 4);
    size_t zlen = (size_t)(p - zbase);
    hipMemsetAsync(zbase, 0, zlen, stream);

    // 8 dispatches (r23: gat1 quarter-split, grid NN blocks; rest frozen)
    fuseA_kernel<<<BNBLK + (ET + 255) / 256, 256, 0, stream>>>(x, colsum1, colsq1, ei, deg);
    fuseB_kernel<<<1 + (NN * KP + 1023) / 1024, 1024, 0, stream>>>(
        deg, offs, cur, perm, x, colsum1, colsq1, gamma1, beta1, hn);
    fuseC_kernel<<<192 + (ET + 255) / 256, 256, 0, stream>>>(Wl1, Wr1, wlt, wrt, ei, cur, ssrc);
    gemm1_kernel<<<dim3((NN + 63) / 64, 16), 256, 0, stream>>>(hn, wlt, wrt, bl1, br1, xl1, xr1);
    gat1_node<<<NN, 256, 0, stream>>>(xl1, xr1, att1, bias1, offs, ssrc, perm, agg);
    bn2_stats<<<125, 256, 0, stream>>>(agg, colsum2, colsq2);
    gemm2_kernel<<<NN / 16, 256, 0, stream>>>(agg, colsum2, colsq2, gamma2, beta2,
                                              Wl2, Wr2, bl2, br2, xl2, xr2);
    gat2_node<<<NN / 4, 256, 0, stream>>>(xl2, xr2, att2, bias2, offs, ssrc, perm, out);
}

// Round 9
// 273.162 us; speedup vs baseline: 1.0664x; 1.0664x over previous
//
#include <hip/hip_runtime.h>

// ---------------- problem constants ----------------
#define NN   10000     // nodes
#define E0   160000    // raw edges
#define ET   170000    // edges + self loops
#define DIN  165       // input channels
#define KP   192       // DIN padded to 32x for MFMA K-loop
#define HID  1024      // 8 heads * 128
#define NH   8
#define AP   200       // gemm1 A-tile LDS pitch (shorts): 2-way banks only, 16B rows
#define CP   136       // gemm1 C-stage LDS pitch (shorts)
#define K2P  1032      // LDS row pitch for gemm2 B
#define BNROW 64       // fuseA bn1 tile rows
#define BNBLK 157      // ceil(NN/BNROW)
#define EHBLK 665      // ceil(ET/256) edge-hist blocks
#define G1BLK (157 * 16)   // gemm1 tile blocks

// dtypes (settled r6): ALL float tensors f32, edge_index int32, OUTPUT f32.

typedef __bf16 bf16x8 __attribute__((ext_vector_type(8)));
typedef float  f32x4  __attribute__((ext_vector_type(4)));
typedef float  f32x2  __attribute__((ext_vector_type(2)));

__device__ __forceinline__ float bf2f(unsigned short u) {
    unsigned int i = ((unsigned int)u) << 16;
    return __builtin_bit_cast(float, i);
}
__device__ __forceinline__ unsigned short f2bf(float f) {
    unsigned int i = __builtin_bit_cast(unsigned int, f);
    i += 0x7fffu + ((i >> 16) & 1u);   // round-to-nearest-even
    return (unsigned short)(i >> 16);
}
__device__ __forceinline__ float fin(float x) {
    return fminf(fmaxf(x, -1e30f), 1e30f);
}
__device__ __forceinline__ int clampi(int s) {
    return min(max(s, 0), NN - 1);
}
__device__ __forceinline__ void unpack8(uint4 u, float* f) {
    f[0]=bf2f((unsigned short)(u.x)); f[1]=bf2f((unsigned short)(u.x>>16));
    f[2]=bf2f((unsigned short)(u.y)); f[3]=bf2f((unsigned short)(u.y>>16));
    f[4]=bf2f((unsigned short)(u.z)); f[5]=bf2f((unsigned short)(u.z>>16));
    f[6]=bf2f((unsigned short)(u.w)); f[7]=bf2f((unsigned short)(u.w>>16));
}
// one packed u32 (2 bf16) -> f32x2 in 2 VALU ops (lshl / and)
__device__ __forceinline__ f32x2 up2(unsigned int u) {
    f32x2 r;
    r.x = __builtin_bit_cast(float, u << 16);
    r.y = __builtin_bit_cast(float, u & 0xffff0000u);
    return r;
}

// ---------------- debug ----------------
__global__ __launch_bounds__(256) void debug_fill(float* __restrict__ out, float val) {
    int i = blockIdx.x * 256 + threadIdx.x;
    if (i < NN) out[i] = val;
}

// ---------------- FUSED A: bn1_stats + edge_hist + w1_transpose (r24) -----------
// All depend only on raw inputs; one dispatch, three blockIdx ranges.
__global__ __launch_bounds__(256) void fuseA_kernel(const float* __restrict__ x,
                                                    float* __restrict__ colsum, float* __restrict__ colsq,
                                                    const int* __restrict__ ei, int* __restrict__ deg,
                                                    const float* __restrict__ wl,
                                                    const float* __restrict__ wr,
                                                    unsigned short* __restrict__ wlt,
                                                    unsigned short* __restrict__ wrt) {
    __shared__ float xs[BNROW * DIN];   // 42.24 KB (bn1 tile; transpose reuses prefix)
    const int b = blockIdx.x;
    const int tid = threadIdx.x;
    if (b < BNBLK) {
        const int r0 = b * BNROW;
        const int nrows = min(BNROW, NN - r0);
        const int total = nrows * DIN;          // even (nrows even)
        const float2* src = (const float2*)(x + (size_t)r0 * DIN);
        float2* dstl = (float2*)xs;
        for (int idx = tid; idx < (total >> 1); idx += 256)
            dstl[idx] = src[idx];
        __syncthreads();
        const int c = tid;
        if (c >= DIN) return;
        float a0=0,a1=0,a2=0,a3=0, q0=0,q1=0,q2=0,q3=0;
        int r = 0;
        for (; r + 3 < nrows; r += 4) {
            float v0 = xs[(r    ) * DIN + c];
            float v1 = xs[(r + 1) * DIN + c];
            float v2 = xs[(r + 2) * DIN + c];
            float v3 = xs[(r + 3) * DIN + c];
            a0 += v0; q0 += v0 * v0;
            a1 += v1; q1 += v1 * v1;
            a2 += v2; q2 += v2 * v2;
            a3 += v3; q3 += v3 * v3;
        }
        for (; r < nrows; ++r) {
            float v = xs[r * DIN + c];
            a0 += v; q0 += v * v;
        }
        atomicAdd(&colsum[c], (a0 + a1) + (a2 + a3));
        atomicAdd(&colsq[c],  (q0 + q1) + (q2 + q3));
    } else if (b < BNBLK + EHBLK) {
        int e = (b - BNBLK) * 256 + tid;
        if (e >= ET) return;
        int d = (e < E0) ? ei[E0 + e] : (e - E0);
        atomicAdd(&deg[clampi(d)], 1);
    } else {
        // w1_transpose: tb -> (kx 0..5, ky 0..15, z 0..1); tile in xs prefix
        const int tb = b - BNBLK - EHBLK;
        const int z  = tb / 96;
        const int rm = tb - z * 96;
        const int ky = rm / 6;
        const int kx = rm - ky * 6;
        const float* src    = z ? wr  : wl;
        unsigned short* dst = z ? wrt : wlt;
        const int k0 = kx * 32;
        const int n0 = ky * 64;
        for (int idx = tid; idx < 32 * 64; idx += 256) {
            int k = idx >> 6, n = idx & 63;
            xs[k * 65 + n] = (k0 + k < DIN) ? src[(size_t)(k0 + k) * HID + n0 + n] : 0.f;
        }
        __syncthreads();
        for (int idx = tid; idx < 64 * 32; idx += 256) {
            int n = idx >> 5, k = idx & 31;
            dst[(size_t)(n0 + n) * KP + k0 + k] = f2bf(xs[k * 65 + n]);
        }
    }
}

// ---------------- FUSED B: scan (block 0, 1024 thr) + bn1_apply (blocks>=1) -----
__global__ __launch_bounds__(1024) void fuseB_kernel(
    const int* __restrict__ deg,
    int* __restrict__ offs, int* __restrict__ cur, int* __restrict__ perm,
    const float* __restrict__ x,
    const float* __restrict__ colsum, const float* __restrict__ colsq,
    const float* __restrict__ gamma, const float* __restrict__ beta,
    unsigned short* __restrict__ hn) {
    if (blockIdx.x != 0) {
        int idx = (blockIdx.x - 1) * 1024 + threadIdx.x;
        if (idx >= NN * KP) return;
        int r = idx / KP, c = idx - r * KP;
        float v = 0.f;
        if (c < DIN) {
            float mu  = colsum[c] * (1.f / NN);
            float var = fmaxf(colsq[c] * (1.f / NN) - mu * mu, 0.f);
            float a = gamma[c] * rsqrtf(var + 1e-5f);
            float b = beta[c] - mu * a;
            v = fin(x[(size_t)r * DIN + c] * a + b);
        }
        hn[idx] = f2bf(v);
        return;
    }
    __shared__ int wsum[16];
    __shared__ int bins[64];
    __shared__ int bcur[64];
    const int tid = threadIdx.x;
    const int base = tid * 10;
    int loc[10];
    int run = 0;
    #pragma unroll
    for (int j = 0; j < 10; ++j) {
        int idx = base + j;
        int v = (idx < NN) ? deg[idx] : 0;
        loc[j] = run;
        run += v;
    }
    const int lane = tid & 63;
    const int w = tid >> 6;
    int inc = run;
    #pragma unroll
    for (int s = 1; s < 64; s <<= 1) {
        int t = __shfl_up(inc, s);
        if (lane >= s) inc += t;
    }
    if (lane == 63) wsum[w] = inc;
    if (tid < 64) bins[tid] = 0;
    __syncthreads();
    int woff = 0;
    #pragma unroll
    for (int k = 0; k < 16; ++k) woff += (k < w) ? wsum[k] : 0;
    const int toff = woff + inc - run;
    #pragma unroll
    for (int j = 0; j < 10; ++j) {
        int idx = base + j;
        if (idx < NN) {
            int e = toff + loc[j]; offs[idx] = e; cur[idx] = e;
            atomicAdd(&bins[63 - min(deg[idx], 63)], 1);   // descending-degree bucket
        }
    }
    if (tid == 1023) offs[NN] = woff + inc;
    __syncthreads();
    if (tid < 64) {   // wave 0: exclusive scan of 64 bins
        int v = bins[tid];
        int binc = v;
        #pragma unroll
        for (int s = 1; s < 64; s <<= 1) {
            int t = __shfl_up(binc, s);
            if (tid >= s) binc += t;
        }
        bcur[tid] = binc - v;
    }
    __syncthreads();
    #pragma unroll
    for (int j = 0; j < 10; ++j) {
        int idx = base + j;
        if (idx < NN) {
            int pos = atomicAdd(&bcur[63 - min(deg[idx], 63)], 1);
            perm[pos] = idx;
        }
    }
}

// ---------------- GEMM1 r24: r20 tiles + edge_scatter blocks appended -----------
// 1D grid: blocks [0, G1BLK) are 64x128 GEMM tiles (bx = b%157 m-tile,
// by = b/157 col-tile); blocks >= G1BLK run edge_scatter (needs only fuseB).
__global__ __launch_bounds__(256) void gemm1_kernel(
    const unsigned short* __restrict__ hn,
    const unsigned short* __restrict__ wlt,  // [HID][KP] bf16
    const unsigned short* __restrict__ wrt,
    const float* __restrict__ bl,
    const float* __restrict__ br,
    unsigned short* __restrict__ xl,
    unsigned short* __restrict__ xr,
    const int* __restrict__ ei,
    int* __restrict__ cur, int* __restrict__ ssrc) {
    __shared__ unsigned short as[64 * AP];   // 25.6 KB: A-tile, then C staging
    const int b = blockIdx.x;
    const int tid = threadIdx.x;
    if (b >= G1BLK) {
        int e = (b - G1BLK) * 256 + tid;
        if (e >= ET) return;
        int s, d;
        if (e < E0) { s = ei[e]; d = ei[E0 + e]; }
        else        { s = e - E0; d = e - E0; }
        int pos = atomicAdd(&cur[clampi(d)], 1);
        if (pos >= 0 && pos < ET) ssrc[pos] = clampi(s);
        return;
    }
    const int bx = b % 157;
    const int by = b / 157;
    const int lane = tid & 63;
    const int wave = tid >> 6;
    const int col  = lane & 15;
    const int q    = lane >> 4;

    const int m0 = bx * 64;
    const int z  = by >> 3;                    // 0 = L half, 1 = R half
    const int nb = (by & 7) * 128;             // col base within that half
    const unsigned short* wt = z ? wrt : wlt;

    // ---- B fragments: 12 batched uint4 loads (L2-resident W'), held in regs ----
    bf16x8 B[2][6];
    {
        const int bc0 = nb + wave * 32 + col;
        #pragma unroll
        for (int nt = 0; nt < 2; ++nt) {
            const unsigned short* wp = wt + (size_t)(bc0 + nt * 16) * KP + q * 8;
            #pragma unroll
            for (int kt = 0; kt < 6; ++kt)
                B[nt][kt] = __builtin_bit_cast(bf16x8, *(const uint4*)(wp + kt * 32));
        }
    }

    // ---- A-tile staging: 6 batched global loads -> 6 LDS writes ----
    {
        const int r  = tid >> 2;               // 0..63
        const int s0 = (tid & 3) * 48;         // short offset within row
        const int grow = m0 + r;
        uint4 t0 = {0,0,0,0}, t1 = t0, t2 = t0, t3 = t0, t4 = t0, t5 = t0;
        if (grow < NN) {
            const unsigned short* gp = hn + (size_t)grow * KP + s0;
            t0 = *(const uint4*)(gp);
            t1 = *(const uint4*)(gp + 8);
            t2 = *(const uint4*)(gp + 16);
            t3 = *(const uint4*)(gp + 24);
            t4 = *(const uint4*)(gp + 32);
            t5 = *(const uint4*)(gp + 40);
        }
        unsigned short* lp = as + r * AP + s0;
        *(uint4*)(lp)      = t0;
        *(uint4*)(lp + 8)  = t1;
        *(uint4*)(lp + 16) = t2;
        *(uint4*)(lp + 24) = t3;
        *(uint4*)(lp + 32) = t4;
        *(uint4*)(lp + 40) = t5;
    }
    __syncthreads();

    // ---- MFMA: 4 m-tiles x 2 n-tiles x 6 k = 48 per wave ----
    f32x4 acc[4][2];
    #pragma unroll
    for (int mi = 0; mi < 4; ++mi)
        for (int nt = 0; nt < 2; ++nt)
            acc[mi][nt][0] = acc[mi][nt][1] = acc[mi][nt][2] = acc[mi][nt][3] = 0.f;

    #pragma unroll
    for (int kt = 0; kt < 6; ++kt) {
        const int kk = kt * 32 + q * 8;
        bf16x8 A[4];
        #pragma unroll
        for (int mi = 0; mi < 4; ++mi)
            A[mi] = __builtin_bit_cast(bf16x8, *(const uint4*)(as + (mi * 16 + col) * AP + kk));
        #pragma unroll
        for (int mi = 0; mi < 4; ++mi) {
            acc[mi][0] = __builtin_amdgcn_mfma_f32_16x16x32_bf16(A[mi], B[0][kt], acc[mi][0], 0, 0, 0);
            acc[mi][1] = __builtin_amdgcn_mfma_f32_16x16x32_bf16(A[mi], B[1][kt], acc[mi][1], 0, 0, 0);
        }
    }

    // ---- epilogue: bias + fin -> LDS C [64][CP], then full 256B-row stores ----
    __syncthreads();                            // A reads done; reuse as[] for C
    #pragma unroll
    for (int nt = 0; nt < 2; ++nt) {
        const int lc = wave * 32 + nt * 16 + col;   // 0..127
        const float bv = (z ? br : bl)[nb + lc];
        #pragma unroll
        for (int mi = 0; mi < 4; ++mi) {
            #pragma unroll
            for (int r = 0; r < 4; ++r) {
                const int lr = mi * 16 + q * 4 + r;
                as[lr * CP + lc] = f2bf(fin(acc[mi][nt][r] + bv));
            }
        }
    }
    __syncthreads();
    {
        const int r  = tid >> 2;               // 0..63
        const int sg = (tid & 3) * 32;         // 32-col (64B) segment
        const int grow = m0 + r;
        if (grow < NN) {
            unsigned short* dst = (z ? xr : xl) + (size_t)grow * HID + nb + sg;
            const unsigned short* sp = as + r * CP + sg;
            *(uint4*)(dst)      = *(const uint4*)(sp);
            *(uint4*)(dst + 8)  = *(const uint4*)(sp + 8);
            *(uint4*)(dst + 16) = *(const uint4*)(sp + 16);
            *(uint4*)(dst + 24) = *(const uint4*)(sp + 24);
        }
    }
}

// ---------------- GAT1 wave-per-node: r15 skeleton + f32x2 packed math ----------
// r24: restored to the proven-best r5 config (49.5us). The structure family is
// fully mapped: r16 ILP pipeline (+2us), r22 2-wave TLP split (+3us), r23 4-way
// channel split (FETCH -50% but VALU +66% -> +12us), r17 8-way (+20us). All
// byte-reduction points cost more instruction time than they save. CLOSED.
__global__ __launch_bounds__(256) void gat1_node(
    const unsigned short* __restrict__ xl1, const unsigned short* xr1,
    const float* __restrict__ att1, const float* __restrict__ bias1,
    const int* __restrict__ offs, const int* __restrict__ ssrc,
    const int* __restrict__ perm,
    unsigned short* agg) {
    const int lane = threadIdx.x & 63;
    const int wave = threadIdx.x >> 6;
    const int i = perm[blockIdx.x * 4 + wave];   // degree-descending
    const int e0 = offs[i];
    const int e1 = max(offs[i + 1], e0);

    f32x2 xr2[8], at2[8], o2[8];
    {
        const uint4* xp = (const uint4*)(xr1 + (size_t)i * HID + lane * 16);
        uint4 u0 = xp[0], u1 = xp[1];
        unsigned int w[8] = {u0.x, u0.y, u0.z, u0.w, u1.x, u1.y, u1.z, u1.w};
        const float4* ap = (const float4*)(att1 + lane * 16);
        float4 a0 = ap[0], a1 = ap[1], a2 = ap[2], a3 = ap[3];
        float af[16] = {a0.x,a0.y,a0.z,a0.w, a1.x,a1.y,a1.z,a1.w,
                        a2.x,a2.y,a2.z,a2.w, a3.x,a3.y,a3.z,a3.w};
        #pragma unroll
        for (int j = 0; j < 8; ++j) {
            xr2[j] = up2(w[j]);
            at2[j].x = af[2*j]; at2[j].y = af[2*j+1];
            o2[j].x = 0.f; o2[j].y = 0.f;
        }
    }
    float s = 0.f;

    int e = e0;
    for (; e + 1 < e1; e += 2) {
        const int s0i = clampi(ssrc[e]);
        const int s1i = clampi(ssrc[e + 1]);
        const uint4* xp0 = (const uint4*)(xl1 + (size_t)s0i * HID + lane * 16);
        const uint4* xp1 = (const uint4*)(xl1 + (size_t)s1i * HID + lane * 16);
        uint4 a0 = xp0[0], a1 = xp0[1], b0 = xp1[0], b1 = xp1[1];
        unsigned int wa[8] = {a0.x,a0.y,a0.z,a0.w, a1.x,a1.y,a1.z,a1.w};
        unsigned int wb[8] = {b0.x,b0.y,b0.z,b0.w, b1.x,b1.y,b1.z,b1.w};
        f32x2 xa[8], xb[8];
        #pragma unroll
        for (int j = 0; j < 8; ++j) { xa[j] = up2(wa[j]); xb[j] = up2(wb[j]); }
        f32x2 pa = {0.f, 0.f}, pb = {0.f, 0.f};
        #pragma unroll
        for (int j = 0; j < 8; ++j) {
            f32x2 va = xa[j] + xr2[j];
            f32x2 vb = xb[j] + xr2[j];
            va = __builtin_elementwise_max(va, 0.2f * va);
            vb = __builtin_elementwise_max(vb, 0.2f * vb);
            pa = __builtin_elementwise_fma(at2[j], va, pa);
            pb = __builtin_elementwise_fma(at2[j], vb, pb);
        }
        float p0 = pa.x + pa.y;
        float p1 = pb.x + pb.y;
        p0 += __shfl_xor(p0, 1); p0 += __shfl_xor(p0, 2); p0 += __shfl_xor(p0, 4);
        p1 += __shfl_xor(p1, 1); p1 += __shfl_xor(p1, 2); p1 += __shfl_xor(p1, 4);
        const float aa0 = __expf(fminf(fin(p0), 50.f));
        const float aa1 = __expf(fminf(fin(p1), 50.f));
        s += aa0 + aa1;
        f32x2 av0; av0.x = aa0; av0.y = aa0;
        f32x2 av1; av1.x = aa1; av1.y = aa1;
        #pragma unroll
        for (int j = 0; j < 8; ++j)
            o2[j] = __builtin_elementwise_fma(av0, xa[j],
                    __builtin_elementwise_fma(av1, xb[j], o2[j]));
    }
    if (e < e1) {
        const int sidx = clampi(ssrc[e]);
        const uint4* xp = (const uint4*)(xl1 + (size_t)sidx * HID + lane * 16);
        uint4 u0 = xp[0], u1 = xp[1];
        unsigned int w[8] = {u0.x,u0.y,u0.z,u0.w, u1.x,u1.y,u1.z,u1.w};
        f32x2 xv[8];
        #pragma unroll
        for (int j = 0; j < 8; ++j) xv[j] = up2(w[j]);
        f32x2 p2 = {0.f, 0.f};
        #pragma unroll
        for (int j = 0; j < 8; ++j) {
            f32x2 v = xv[j] + xr2[j];
            v = __builtin_elementwise_max(v, 0.2f * v);
            p2 = __builtin_elementwise_fma(at2[j], v, p2);
        }
        float p = p2.x + p2.y;
        p += __shfl_xor(p, 1); p += __shfl_xor(p, 2); p += __shfl_xor(p, 4);
        const float a = __expf(fminf(fin(p), 50.f));
        s += a;
        f32x2 av; av.x = a; av.y = a;
        #pragma unroll
        for (int j = 0; j < 8; ++j)
            o2[j] = __builtin_elementwise_fma(av, xv[j], o2[j]);
    }

    const float inv = 1.f / (s + 1e-16f);
    const float4* bp = (const float4*)(bias1 + lane * 16);
    float4 b0 = bp[0], b1 = bp[1], b2 = bp[2], b3 = bp[3];
    float bb[16] = {b0.x,b0.y,b0.z,b0.w, b1.x,b1.y,b1.z,b1.w,
                    b2.x,b2.y,b2.z,b2.w, b3.x,b3.y,b3.z,b3.w};
    unsigned short ov[16];
    #pragma unroll
    for (int j = 0; j < 8; ++j) {
        ov[2*j]   = f2bf(fin(o2[j].x * inv + bb[2*j]));
        ov[2*j+1] = f2bf(fin(o2[j].y * inv + bb[2*j+1]));
    }
    uint4* op = (uint4*)(agg + (size_t)i * HID + lane * 16);
    op[0] = *(const uint4*)&ov[0];
    op[1] = *(const uint4*)&ov[8];
}

// ---------------- BN2 stats over agg [NN,HID] bf16 ----------------
__global__ __launch_bounds__(256) void bn2_stats(const unsigned short* __restrict__ agg,
                                                 float* __restrict__ colsum, float* __restrict__ colsq) {
    __shared__ float mrg[128 * 16];   // 8 KB: half-1 partials
    const int tid  = threadIdx.x;
    const int half = tid >> 7;        // 0/1
    const int cc   = (tid & 127) * 8; // column base (8 cols per thread)
    const int r0   = blockIdx.x * 80 + half;
    float s[8], q[8];
    #pragma unroll
    for (int j = 0; j < 8; ++j) { s[j] = 0.f; q[j] = 0.f; }
    #pragma unroll 4
    for (int rr = 0; rr < 40; ++rr) {
        const int r = r0 + rr * 2;
        uint4 u = *(const uint4*)(agg + (size_t)r * HID + cc);
        float v[8];
        unpack8(u, v);
        #pragma unroll
        for (int j = 0; j < 8; ++j) { s[j] += v[j]; q[j] += v[j] * v[j]; }
    }
    if (half) {
        float* m = &mrg[(tid & 127) * 16];
        #pragma unroll
        for (int j = 0; j < 8; ++j) { m[j] = s[j]; m[8 + j] = q[j]; }
    }
    __syncthreads();
    if (!half) {
        const float* m = &mrg[tid * 16];
        #pragma unroll
        for (int j = 0; j < 8; ++j) {
            atomicAdd(&colsum[cc + j], s[j] + m[j]);
            atomicAdd(&colsq[cc + j],  q[j] + m[8 + j]);
        }
    }
}

// ---------------- GEMM2 (K split across 4 waves + LDS reduce; grid 625) ----
__global__ __launch_bounds__(256) void gemm2_kernel(
    const unsigned short* __restrict__ agg,
    const float* __restrict__ colsum, const float* __restrict__ colsq,
    const float* __restrict__ gamma, const float* __restrict__ beta,
    const float* __restrict__ wl2, const float* __restrict__ wr2,
    const float* __restrict__ bl2, const float* __restrict__ br2,
    float* __restrict__ xl2, float* __restrict__ xr2) {
    __shared__ unsigned short bs[16 * K2P];   // 33 KB
    __shared__ float a2s[HID], b2s[HID];      // 8 KB affine table
    __shared__ float red[4 * 64 * 4];         // 4 KB wave partials
    const int tid  = threadIdx.x;
    const int lane = tid & 63;
    const int wave = tid >> 6;
    const int col  = lane & 15;
    const int q    = lane >> 4;

    for (int idx = tid; idx < 16 * HID; idx += 256) {
        int n = idx >> 10, k = idx & (HID - 1);
        float v = (n < 8) ? wl2[k * 8 + n] : wr2[k * 8 + (n - 8)];
        bs[n * K2P + k] = f2bf(v);
    }
    for (int cc = tid; cc < HID; cc += 256) {
        float mu  = colsum[cc] * (1.f / NN);
        float var = fmaxf(colsq[cc] * (1.f / NN) - mu * mu, 0.f);
        float a = gamma[cc] * rsqrtf(var + 1e-5f);
        a2s[cc] = a; b2s[cc] = beta[cc] - mu * a;
    }
    __syncthreads();

    const int m0 = blockIdx.x * 16;
    const int am = m0 + col;

    // hoist all 8 independent A-row loads
    uint4 u[8];
    #pragma unroll
    for (int t = 0; t < 8; ++t) {
        const int kk = (wave * 8 + t) * 32 + q * 8;
        u[t] = *(const uint4*)(agg + (size_t)am * HID + kk);
    }

    f32x4 acc;
    acc[0] = acc[1] = acc[2] = acc[3] = 0.f;
    #pragma unroll
    for (int t = 0; t < 8; ++t) {
        const int kk = (wave * 8 + t) * 32 + q * 8;
        float xv[8];
        unpack8(u[t], xv);
        unsigned short hv[8];
        #pragma unroll
        for (int j = 0; j < 8; ++j) {
            float v = xv[j] * a2s[kk + j] + b2s[kk + j];
            v = fmaxf(v, 0.01f * v);          // leaky 0.01
            hv[j] = f2bf(fin(v));
        }
        bf16x8 af = __builtin_bit_cast(bf16x8, *(const uint4*)hv);
        bf16x8 bf = __builtin_bit_cast(bf16x8, *(const uint4*)&bs[col * K2P + kk]);
        acc = __builtin_amdgcn_mfma_f32_16x16x32_bf16(af, bf, acc, 0, 0, 0);
    }

    *(f32x4*)&red[(wave * 64 + lane) * 4] = acc;
    __syncthreads();
    if (wave == 0) {
        f32x4 a0 = *(const f32x4*)&red[lane * 4];
        f32x4 a1 = *(const f32x4*)&red[(64 + lane) * 4];
        f32x4 a2 = *(const f32x4*)&red[(128 + lane) * 4];
        f32x4 a3 = *(const f32x4*)&red[(192 + lane) * 4];
        acc = (a0 + a1) + (a2 + a3);
        const float bv = (col < 8) ? bl2[col] : br2[col - 8];
        float* outp = (col < 8) ? (xl2 + col) : (xr2 + (col - 8));
        #pragma unroll
        for (int r = 0; r < 4; ++r) {
            const int row = m0 + q * 4 + r;
            outp[row * 8] = fin(acc[r] + bv);
        }
    }
}

// ---------------- GAT2 single-pass (degree-sorted order) ----------------
__global__ __launch_bounds__(256) void gat2_node(
    const float* __restrict__ xl2, const float* __restrict__ xr2,
    const float* __restrict__ att2, const float* __restrict__ bias2,
    const int* __restrict__ offs, const int* __restrict__ ssrc,
    const int* __restrict__ perm,
    float* __restrict__ out) {
    const int lane = threadIdx.x & 63;
    const int wave = threadIdx.x >> 6;
    const int i = perm[blockIdx.x * 4 + wave];
    const int h = lane & 7, slot = lane >> 3;
    const int e0 = offs[i];
    const int e1 = max(offs[i + 1], e0);
    const float xr_h = xr2[i * 8 + h];
    const float att_h = att2[h];
    float ssum = 0.f, wsum = 0.f;
    for (int eb = e0; eb < e1; eb += 8) {
        int e = eb + slot;
        if (e < e1) {
            float xlv = xl2[clampi(ssrc[e]) * 8 + h];
            float v = xlv + xr_h;
            v = fmaxf(v, 0.2f * v);
            float a = __expf(fminf(fin(att_h * v), 50.f));
            ssum += a; wsum += a * xlv;
        }
    }
    ssum += __shfl_xor(ssum, 8); ssum += __shfl_xor(ssum, 16); ssum += __shfl_xor(ssum, 32);
    wsum += __shfl_xor(wsum, 8); wsum += __shfl_xor(wsum, 16); wsum += __shfl_xor(wsum, 32);
    float v = fin(wsum / (ssum + 1e-16f));
    v += __shfl_xor(v, 1); v += __shfl_xor(v, 2); v += __shfl_xor(v, 4);
    if (lane == 0) out[i] = fin(v * 0.125f + bias2[0]);
}

// ---------------- launch ----------------
extern "C" void kernel_launch(void* const* d_in, const int* in_sizes, int n_in,
                              void* d_out, int out_size, void* d_ws, size_t ws_size,
                              hipStream_t stream) {
    float* out = (float*)d_out;   // reference output dtype is float32

    static const int expected[18] = {
        NN * DIN, DIN, DIN, DIN * HID, HID, DIN * HID, HID, HID, HID,
        HID, HID, HID * NH, NH, HID * NH, NH, NH, 1, 2 * E0
    };
    if (n_in != 18) {
        debug_fill<<<(NN + 255) / 256, 256, 0, stream>>>(out, 8192.f + 64.f * (float)n_in);
        return;
    }
    for (int i = 0; i < 18; ++i) {
        if (in_sizes[i] != expected[i]) {
            debug_fill<<<(NN + 255) / 256, 256, 0, stream>>>(out, 4096.f + 32.f * (float)i);
            return;
        }
    }

    const float* x      = (const float*)d_in[0];
    const float* gamma1 = (const float*)d_in[1];
    const float* beta1  = (const float*)d_in[2];
    const float* Wl1    = (const float*)d_in[3];
    const float* bl1    = (const float*)d_in[4];
    const float* Wr1    = (const float*)d_in[5];
    const float* br1    = (const float*)d_in[6];
    const float* att1   = (const float*)d_in[7];
    const float* bias1  = (const float*)d_in[8];
    const float* gamma2 = (const float*)d_in[9];
    const float* beta2  = (const float*)d_in[10];
    const float* Wl2    = (const float*)d_in[11];
    const float* bl2    = (const float*)d_in[12];
    const float* Wr2    = (const float*)d_in[13];
    const float* br2    = (const float*)d_in[14];
    const float* att2   = (const float*)d_in[15];
    const float* bias2  = (const float*)d_in[16];
    const int*   ei     = (const int*)d_in[17];

    char* p = (char*)d_ws;
    auto alloc = [&](size_t bytes) -> void* {
        void* r = (void*)p;
        p += (bytes + 255) & ~(size_t)255;
        return r;
    };
    unsigned short* xl1  = (unsigned short*)alloc((size_t)NN * HID * 2);  // 20.48 MB
    unsigned short* xr1  = (unsigned short*)alloc((size_t)NN * HID * 2);  // 20.48 MB
    unsigned short* agg  = xr1;                                           // ALIAS (see gat1_node)
    unsigned short* hn   = (unsigned short*)alloc((size_t)NN * KP * 2);   // 3.84 MB
    unsigned short* wlt  = (unsigned short*)alloc((size_t)HID * KP * 2);  // 0.39 MB
    unsigned short* wrt  = (unsigned short*)alloc((size_t)HID * KP * 2);  // 0.39 MB
    float*          xl2  = (float*)alloc((size_t)NN * 8 * 4);
    float*          xr2  = (float*)alloc((size_t)NN * 8 * 4);
    int*            offs = (int*)alloc((NN + 1) * 4);
    int*            cur  = (int*)alloc(NN * 4);
    int*            ssrc = (int*)alloc(ET * 4);
    int*            perm = (int*)alloc(NN * 4);
    char* zbase = p;
    float* colsum1 = (float*)alloc(DIN * 4);
    float* colsq1  = (float*)alloc(DIN * 4);
    float* colsum2 = (float*)alloc(HID * 4);
    float* colsq2  = (float*)alloc(HID * 4);
    int*   deg     = (int*)alloc(NN * 4);
    size_t zlen = (size_t)(p - zbase);
    hipMemsetAsync(zbase, 0, zlen, stream);

    // 7 dispatches (r24: transpose folded into fuseA, scatter into gemm1;
    // gat1 restored to proven-best r5 config). Chain is now pure data deps.
    fuseA_kernel<<<BNBLK + EHBLK + 192, 256, 0, stream>>>(
        x, colsum1, colsq1, ei, deg, Wl1, Wr1, wlt, wrt);
    fuseB_kernel<<<1 + (NN * KP + 1023) / 1024, 1024, 0, stream>>>(
        deg, offs, cur, perm, x, colsum1, colsq1, gamma1, beta1, hn);
    gemm1_kernel<<<G1BLK + EHBLK, 256, 0, stream>>>(
        hn, wlt, wrt, bl1, br1, xl1, xr1, ei, cur, ssrc);
    gat1_node<<<NN / 4, 256, 0, stream>>>(xl1, xr1, att1, bias1, offs, ssrc, perm, agg);
    bn2_stats<<<125, 256, 0, stream>>>(agg, colsum2, colsq2);
    gemm2_kernel<<<NN / 16, 256, 0, stream>>>(agg, colsum2, colsq2, gamma2, beta2,
                                              Wl2, Wr2, bl2, br2, xl2, xr2);
    gat2_node<<<NN / 4, 256, 0, stream>>>(xl2, xr2, att2, bias2, offs, ssrc, perm, out);
}